// Round 13
// baseline (114.498 us; speedup 1.0000x reference)
//
#include <hip/hip_runtime.h>
#include <hip/hip_bf16.h>

using ushort = unsigned short;

typedef __attribute__((ext_vector_type(8))) short bf16x8;
typedef __attribute__((ext_vector_type(4))) float f32x4;
typedef __attribute__((ext_vector_type(16))) float f32x16;
typedef __attribute__((ext_vector_type(4))) unsigned short u16x4;

#define DEVINL __device__ __forceinline__

// ---- problem constants ----
// B=2, S=2048, D=1024, H=16, dk=64, M=B*S=4096

// workspace layout (ushort element offsets)
static constexpr size_t WQ_O = 12582912;       // weights bf16, 1M each (wq,wk,wv,wo)
static constexpr size_t WO_O = 15728640;
static constexpr size_t QB_O = 16777216;       // Q [b][h][s][64]   4M  (scaled by log2e/8)
static constexpr size_t KB_O = 20971520;       // K [b][h][s][64]   4M
static constexpr size_t VT_O = 25165824;       // V^T [b][h][64][s] 4M
static constexpr size_t CTX_O = 0;             // ctx [b][s][1024] bf16

DEVINL ushort f2bf(float f) {
  unsigned u = __builtin_bit_cast(unsigned, f);
  u += 0x7fffu + ((u >> 16) & 1u);   // RNE
  return (ushort)(u >> 16);
}

// async global->LDS DMA, 16B per lane; dst wave-uniform base (HW adds lane*16)
DEVINL void gld16(const ushort* g, ushort* lds) {
  __builtin_amdgcn_global_load_lds(
      (const __attribute__((address_space(1))) void*)g,
      (__attribute__((address_space(3))) void*)lds, 16, 0, 0);
}

// ---------------- fp32 -> bf16 conversion of the 4 weight matrices ----------------
__global__ __launch_bounds__(256) void cvt_w(
    const float* __restrict__ wq, const float* __restrict__ wk,
    const float* __restrict__ wv, const float* __restrict__ wo,
    ushort* __restrict__ ws)
{
  int e = (blockIdx.x * 256 + threadIdx.x) * 8;   // 4M elems total
  const float* s;
  if      (e < 1048576) s = wq + e;
  else if (e < 2097152) s = wk + (e - 1048576);
  else if (e < 3145728) s = wv + (e - 2097152);
  else                  s = wo + (e - 3145728);
  float4 a = *(const float4*)s;
  float4 b = *(const float4*)(s + 4);
  union { u16x4 v; ushort u[4]; } r0, r1;
  r0.u[0] = f2bf(a.x); r0.u[1] = f2bf(a.y); r0.u[2] = f2bf(a.z); r0.u[3] = f2bf(a.w);
  r1.u[0] = f2bf(b.x); r1.u[1] = f2bf(b.y); r1.u[2] = f2bf(b.z); r1.u[3] = f2bf(b.w);
  *(u16x4*)(ws + WQ_O + e) = r0.v;
  *(u16x4*)(ws + WQ_O + e + 4) = r1.v;
}

// ---------------- 128xBN bf16 NT GEMM core (y = x @ W^T + b) ----------------
// CVTA: A is fp32, converted to bf16 during LDS staging (v_cvt_pk_bf16_f32).
template<bool CVTA, int BN>
DEVINL void gemm_core(const void* __restrict__ Av, const ushort* __restrict__ Bw,
                      const float* __restrict__ bias, void* __restrict__ Cout,
                      float scale, int omode, int row0, int col0)
{
  constexpr int K = 1024;
  constexpr int BI = BN / 32;
  constexpr int NJ = BN / 32;
  __shared__ ushort As[128 * 64];
  __shared__ ushort Bs[BN * 64];
  const int t = threadIdx.x;
  const int l = t & 63;
  const int w = t >> 6;
  const int wr = w >> 1, wc = w & 1;

  const int srow = t >> 3;
  const int scol8 = (t & 7) * 8;
  const int swz_half = ((((t & 7) * 16) ^ ((srow & 7) << 4)) >> 1);

  const ushort* Ap16 = (const ushort*)Av + (size_t)(row0 + srow) * K + scol8;
  const float*  Ap32 = (const float*)Av + (size_t)(row0 + srow) * K + scol8;
  const ushort* Bp = Bw + (size_t)(col0 + srow) * K + scol8;

  bf16x8 areg[4], breg[BI];
  float4 a32[4][2];
  auto loadstage = [&](int k0) {
#pragma unroll
    for (int i = 0; i < 4; ++i) {
      if constexpr (CVTA) {
        a32[i][0] = *(const float4*)(Ap32 + (size_t)(i * 32) * K + k0);
        a32[i][1] = *(const float4*)(Ap32 + (size_t)(i * 32) * K + k0 + 4);
      } else {
        areg[i] = *(const bf16x8*)(Ap16 + (size_t)(i * 32) * K + k0);
      }
    }
#pragma unroll
    for (int i = 0; i < BI; ++i)
      breg[i] = *(const bf16x8*)(Bp + (size_t)(i * 32) * K + k0);
  };

  f32x4 acc[4][NJ];
#pragma unroll
  for (int i = 0; i < 4; ++i)
#pragma unroll
    for (int j = 0; j < NJ; ++j) acc[i][j] = (f32x4){0.f, 0.f, 0.f, 0.f};

  loadstage(0);
#pragma unroll 1
  for (int kt = 0; kt < K / 64; ++kt) {
    __syncthreads();
#pragma unroll
    for (int i = 0; i < 4; ++i) {
      if constexpr (CVTA) {
        union { bf16x8 v; unsigned u[4]; } pk;
        asm("v_cvt_pk_bf16_f32 %0, %1, %2" : "=v"(pk.u[0]) : "v"(a32[i][0].x), "v"(a32[i][0].y));
        asm("v_cvt_pk_bf16_f32 %0, %1, %2" : "=v"(pk.u[1]) : "v"(a32[i][0].z), "v"(a32[i][0].w));
        asm("v_cvt_pk_bf16_f32 %0, %1, %2" : "=v"(pk.u[2]) : "v"(a32[i][1].x), "v"(a32[i][1].y));
        asm("v_cvt_pk_bf16_f32 %0, %1, %2" : "=v"(pk.u[3]) : "v"(a32[i][1].z), "v"(a32[i][1].w));
        *(bf16x8*)&As[(srow + i * 32) * 64 + swz_half] = pk.v;
      } else {
        *(bf16x8*)&As[(srow + i * 32) * 64 + swz_half] = areg[i];
      }
    }
#pragma unroll
    for (int i = 0; i < BI; ++i)
      *(bf16x8*)&Bs[(srow + i * 32) * 64 + swz_half] = breg[i];
    if (kt + 1 < K / 64) loadstage((kt + 1) * 64);
    __syncthreads();
#pragma unroll
    for (int ks = 0; ks < 2; ++ks) {
      bf16x8 af[4], bfr[NJ];
#pragma unroll
      for (int mi = 0; mi < 4; ++mi) {
        int r = wr * 64 + mi * 16 + (l & 15);
        int cb = ((ks << 6) | ((l >> 4) << 4)) ^ ((r & 7) << 4);
        af[mi] = *(const bf16x8*)&As[r * 64 + (cb >> 1)];
      }
#pragma unroll
      for (int nj = 0; nj < NJ; ++nj) {
        int r = wc * (BN / 2) + nj * 16 + (l & 15);
        int cb = ((ks << 6) | ((l >> 4) << 4)) ^ ((r & 7) << 4);
        bfr[nj] = *(const bf16x8*)&Bs[r * 64 + (cb >> 1)];
      }
#pragma unroll
      for (int mi = 0; mi < 4; ++mi)
#pragma unroll
        for (int nj = 0; nj < NJ; ++nj)
          acc[mi][nj] = __builtin_amdgcn_mfma_f32_16x16x32_bf16(af[mi], bfr[nj], acc[mi][nj], 0, 0, 0);
    }
  }

  const int cl = l & 15;
#pragma unroll
  for (int mi = 0; mi < 4; ++mi) {
#pragma unroll
    for (int nj = 0; nj < NJ; ++nj) {
      int n = col0 + wc * (BN / 2) + nj * 16 + cl;
      float bv = bias[n];
      int mbase = row0 + wr * 64 + mi * 16 + (l >> 4) * 4;
      if (omode == 1) {
        float* Of = (float*)Cout;
#pragma unroll
        for (int ri = 0; ri < 4; ++ri)
          Of[(size_t)(mbase + ri) * 1024 + n] = (acc[mi][nj][ri] + bv) * scale;
      } else if (omode == 0) {
        ushort* Ob = (ushort*)Cout;
        int h = n >> 6, d = n & 63;
#pragma unroll
        for (int ri = 0; ri < 4; ++ri) {
          int m = mbase + ri;
          int b = m >> 11, s = m & 2047;
          Ob[(size_t)((b * 16 + h) * 2048 + s) * 64 + d] = f2bf((acc[mi][nj][ri] + bv) * scale);
        }
      } else {  // omode 2: transposed V layout [b][h][d][s]
        ushort* Ob = (ushort*)Cout;
        int h = n >> 6, d = n & 63;
        int b = mbase >> 11, s = mbase & 2047;
        union { u16x4 v; ushort u[4]; } pk;
#pragma unroll
        for (int ri = 0; ri < 4; ++ri) pk.u[ri] = f2bf((acc[mi][nj][ri] + bv) * scale);
        *(u16x4*)&Ob[(size_t)((b * 16 + h) * 64 + d) * 2048 + s] = pk.v;
      }
    }
  }
}

// fused QKV projection + fp32->bf16 A conversion, BN=64 tiles for occupancy.
// grid (8, 192): X = blockIdx.x = XCD; j = blockIdx.y; group g = 8*(j>>4)+X identifies
// (z = g>>5, by = g&31); bx = j&15. All 16 bx-blocks sharing one fp32 A-panel stay on
// XCD X -> one L2 fetch per panel. 1536 blocks = 6 blocks/CU (latency-hiding).
__global__ __launch_bounds__(256, 2) void gemm_qkv(
    const float* __restrict__ xq, const float* __restrict__ xk, const float* __restrict__ xv,
    const ushort* __restrict__ ws_c, ushort* __restrict__ ws_m,
    const float* __restrict__ bq, const float* __restrict__ bk, const float* __restrict__ bv)
{
  const int X = blockIdx.x, j = blockIdx.y;
  const int g = 8 * (j >> 4) + X;      // 0..95
  const int bx = j & 15;
  const int by = g & 31, z = g >> 5;

  const float* A = (z == 0) ? xq : ((z == 1) ? xk : xv);
  const ushort* W = ws_c + WQ_O + (size_t)z * 1048576;
  const float* bias = (z == 0) ? bq : ((z == 1) ? bk : bv);
  ushort* dst = ws_m + QB_O + (size_t)z * 4194304;
  float scale = (z == 0) ? (0.125f * 1.4426950408889634f) : 1.0f;  // fold 1/sqrt(dk)*log2e into Q
  int omode = (z == 2) ? 2 : 0;
  gemm_core<true, 64>(A, W, bias, dst, scale, omode, by * 128, bx * 64);
}

// out projection: 128x64 tiles -> 512 blocks = 2 blocks/CU
__global__ __launch_bounds__(256, 2) void gemm_out(
    const ushort* __restrict__ ctx, const ushort* __restrict__ wo,
    const float* __restrict__ bo, float* __restrict__ out)
{
  gemm_core<false, 64>(ctx, wo, bo, out, 1.0f, 1, blockIdx.y * 128, blockIdx.x * 64);
}

// ---------------- flash attention (R10 bench-proven, verbatim) ----------------
__global__ __launch_bounds__(512, 4) void attn8(
    const ushort* __restrict__ Qb, const ushort* __restrict__ Kb,
    const ushort* __restrict__ Vtb, ushort* __restrict__ Ctx)
{
  __shared__ ushort smem[32768];   // 64KB: K[half][buf][4096] | +16384: V[half][buf][4096]

  const int t = threadIdx.x, l = t & 63, w = t >> 6;
  const int wq4 = w & 3, half = w >> 2;
  const int hi2 = l >> 5, q = l & 31;

  // XCD-aware remap: hw dispatch-linear; xcd = hw&7 -> bh%8 == xcd
  const int hw = blockIdx.y * 16 + blockIdx.x;
  const int j = hw >> 3;
  const int bh = (hw & 7) + 8 * (j >> 4);
  const int qt = j & 15;

  const int kvb = half * 1024;
  const ushort* Qp = Qb + ((size_t)bh * 2048 + qt * 128 + wq4 * 32) * 64;
  const ushort* Kp = Kb + (size_t)bh * 2048 * 64;
  const ushort* Vp = Vtb + (size_t)bh * 64 * 2048;

  ushort* Ksh = smem + half * 8192;
  ushort* Vsh = smem + 16384 + half * 8192;

  // Q B-fragments: lane holds Q[q][ks*16 + hi2*8 + j]
  bf16x8 qf[4];
#pragma unroll
  for (int ks = 0; ks < 4; ++ks)
    qf[ks] = *(const bf16x8*)(Qp + q * 64 + ks * 16 + hi2 * 8);

  auto stageKV = [&](int pp, int kv0) {
#pragma unroll
    for (int i = 0; i < 2; ++i) {
      int R = (i * 4 + wq4) * 8 + (l >> 3);                     // LDS row 0..63
      int g = l & 7;                                            // 16B granule
      int sR = (R & ~12) | ((R & 4) << 1) | ((R & 8) >> 1);     // swap bits 2,3
      gld16(Kp + (size_t)(kv0 + sR) * 64 + (g ^ (R & 7)) * 8,
            Ksh + pp * 4096 + (i * 4 + wq4) * 512);
      gld16(Vp + (size_t)R * 2048 + kv0 + (g ^ (R & 7)) * 8,
            Vsh + pp * 4096 + (i * 4 + wq4) * 512);
    }
  };

  f32x16 acc0, acc1;   // N^T: d = db*32 + (reg&3)+8*(reg>>2)+4*hi2, col q
#pragma unroll
  for (int i = 0; i < 16; ++i) { acc0[i] = 0.f; acc1[i] = 0.f; }
  f32x16 Zv;
#pragma unroll
  for (int i = 0; i < 16; ++i) Zv[i] = 0.f;
  float lrun = 0.f;

  const int rsw = (q & 7) << 4;

  stageKV(0, kvb);
  __syncthreads();

#pragma unroll 1
  for (int kt = 0; kt < 16; ++kt) {
    const int p = kt & 1;
    const ushort* Kl = Ksh + p * 4096;
    const ushort* Vl = Vsh + p * 4096;

    // ---- QK burst: both 32-kv chunks (8 MFMA back-to-back, C = persistent zero) ----
    f32x16 scA, scB;
    __builtin_amdgcn_s_setprio(1);
    {
      bf16x8 kf = *(const bf16x8*)&Kl[q * 64 + (((hi2 * 16)) ^ rsw) / 2];
      scA = __builtin_amdgcn_mfma_f32_32x32x16_bf16(kf, qf[0], Zv, 0, 0, 0);
#pragma unroll
      for (int ks = 1; ks < 4; ++ks) {
        bf16x8 k2 = *(const bf16x8*)&Kl[q * 64 + (((ks * 32 + hi2 * 16) ^ rsw) >> 1)];
        scA = __builtin_amdgcn_mfma_f32_32x32x16_bf16(k2, qf[ks], scA, 0, 0, 0);
      }
      const int r1 = (32 + q) * 64;
      bf16x8 kg = *(const bf16x8*)&Kl[r1 + (((hi2 * 16)) ^ rsw) / 2];
      scB = __builtin_amdgcn_mfma_f32_32x32x16_bf16(kg, qf[0], Zv, 0, 0, 0);
#pragma unroll
      for (int ks = 1; ks < 4; ++ks) {
        bf16x8 k2 = *(const bf16x8*)&Kl[r1 + (((ks * 32 + hi2 * 16) ^ rsw) >> 1)];
        scB = __builtin_amdgcn_mfma_f32_32x32x16_bf16(k2, qf[ks], scB, 0, 0, 0);
      }
    }
    __builtin_amdgcn_s_setprio(0);

    if (kt + 1 < 16) stageKV(p ^ 1, kvb + (kt + 1) * 64);

    // ---- per chunk: softmax-lite + pack + PV ----
#pragma unroll
    for (int c = 0; c < 2; ++c) {
      f32x16& sc = (c == 0) ? scA : scB;
      float s0 = 0.f, s1 = 0.f, s2 = 0.f, s3 = 0.f;
#pragma unroll
      for (int i = 0; i < 4; ++i) {
        float e0 = __builtin_amdgcn_exp2f(sc[i]);      sc[i] = e0;      s0 += e0;
        float e1 = __builtin_amdgcn_exp2f(sc[4 + i]);  sc[4 + i] = e1;  s1 += e1;
        float e2 = __builtin_amdgcn_exp2f(sc[8 + i]);  sc[8 + i] = e2;  s2 += e2;
        float e3 = __builtin_amdgcn_exp2f(sc[12 + i]); sc[12 + i] = e3; s3 += e3;
      }
      lrun += (s0 + s1) + (s2 + s3);

      union PU { bf16x8 v; unsigned u[4]; } pA, pB;
#pragma unroll
      for (int i = 0; i < 4; ++i) {
        asm("v_cvt_pk_bf16_f32 %0, %1, %2" : "=v"(pA.u[i]) : "v"(sc[2 * i]), "v"(sc[2 * i + 1]));
        asm("v_cvt_pk_bf16_f32 %0, %1, %2" : "=v"(pB.u[i]) : "v"(sc[8 + 2 * i]), "v"(sc[9 + 2 * i]));
      }

      __builtin_amdgcn_s_setprio(1);
#pragma unroll
      for (int db = 0; db < 2; ++db) {
        const int d = db * 32 + q;
        bf16x8 va = *(const bf16x8*)&Vl[d * 64 + (((c * 64 + hi2 * 16) ^ rsw) >> 1)];
        bf16x8 vb = *(const bf16x8*)&Vl[d * 64 + (((c * 64 + 32 + hi2 * 16) ^ rsw) >> 1)];
        if (db == 0) {
          acc0 = __builtin_amdgcn_mfma_f32_32x32x16_bf16(va, pA.v, acc0, 0, 0, 0);
          acc0 = __builtin_amdgcn_mfma_f32_32x32x16_bf16(vb, pB.v, acc0, 0, 0, 0);
        } else {
          acc1 = __builtin_amdgcn_mfma_f32_32x32x16_bf16(va, pA.v, acc1, 0, 0, 0);
          acc1 = __builtin_amdgcn_mfma_f32_32x32x16_bf16(vb, pB.v, acc1, 0, 0, 0);
        }
      }
      __builtin_amdgcn_s_setprio(0);
    }
    __syncthreads();
  }

  // ===== epilogue: merge halves in LDS (granule-swizzled), coalesced ctx write =====
  float lsum = lrun + __shfl_xor(lrun, 32);
  float* Lf = (float*)smem;

  // phase A: merge row-sums (1KB region)
  if (l < 32) Lf[half * 128 + wq4 * 32 + q] = lsum;
  __syncthreads();
  const float inv = 1.0f / (Lf[wq4 * 32 + q] + Lf[128 + wq4 * 32 + q]);
  __syncthreads();

  // swizzled float4-granule address: row stride 64 floats, G' = G ^ (row&15)
  auto mrg = [&](int row, int G) -> float* {
    return Lf + row * 64 + ((G ^ (row & 15)) << 2);
  };

  // phase B: half1 dumps raw partials
  if (half == 1) {
    const int row = wq4 * 32 + q;
#pragma unroll
    for (int db = 0; db < 2; ++db)
#pragma unroll
      for (int g = 0; g < 4; ++g) {
        float4 v;
        if (db == 0) v = (float4){acc0[g * 4], acc0[g * 4 + 1], acc0[g * 4 + 2], acc0[g * 4 + 3]};
        else         v = (float4){acc1[g * 4], acc1[g * 4 + 1], acc1[g * 4 + 2], acc1[g * 4 + 3]};
        *(float4*)mrg(row, db * 8 + g * 2 + hi2) = v;
      }
  }
  __syncthreads();

  // phase C: half0 merges in place, applying 1/l
  if (half == 0) {
    const int row = wq4 * 32 + q;
#pragma unroll
    for (int db = 0; db < 2; ++db)
#pragma unroll
      for (int g = 0; g < 4; ++g) {
        float* p = mrg(row, db * 8 + g * 2 + hi2);
        float4 pv = *(float4*)p;
        float4 o;
        if (db == 0) o = (float4){(acc0[g * 4] + pv.x) * inv, (acc0[g * 4 + 1] + pv.y) * inv,
                                  (acc0[g * 4 + 2] + pv.z) * inv, (acc0[g * 4 + 3] + pv.w) * inv};
        else         o = (float4){(acc1[g * 4] + pv.x) * inv, (acc1[g * 4 + 1] + pv.y) * inv,
                                  (acc1[g * 4 + 2] + pv.z) * inv, (acc1[g * 4 + 3] + pv.w) * inv};
        *(float4*)p = o;
      }
  }
  __syncthreads();

  // phase D: all 8 waves write ctx; 8 lanes cover one 128B row
  {
    const int b = bh >> 4, h = bh & 15;
    const int d0 = (l & 7) * 8;
#pragma unroll
    for (int rr = 0; rr < 2; ++rr) {
      int row = w * 16 + rr * 8 + (l >> 3);
      float4 f0 = *(const float4*)mrg(row, (l & 7) * 2);
      float4 f1 = *(const float4*)mrg(row, (l & 7) * 2 + 1);
      union { u16x4 v; ushort u[4]; } o0, o1;
      o0.u[0] = f2bf(f0.x); o0.u[1] = f2bf(f0.y); o0.u[2] = f2bf(f0.z); o0.u[3] = f2bf(f0.w);
      o1.u[0] = f2bf(f1.x); o1.u[1] = f2bf(f1.y); o1.u[2] = f2bf(f1.z); o1.u[3] = f2bf(f1.w);
      ushort* dst = Ctx + ((size_t)b * 2048 + qt * 128 + row) * 1024 + h * 64 + d0;
      *(u16x4*)dst = o0.v;
      *(u16x4*)(dst + 4) = o1.v;
    }
  }
}

extern "C" void kernel_launch(void* const* d_in, const int* in_sizes, int n_in,
                              void* d_out, int out_size, void* d_ws, size_t ws_size,
                              hipStream_t stream) {
  const float* xq = (const float*)d_in[0];
  const float* xk = (const float*)d_in[1];
  const float* xv = (const float*)d_in[2];
  const float* wq = (const float*)d_in[3];
  const float* bq = (const float*)d_in[4];
  const float* wk = (const float*)d_in[5];
  const float* bk = (const float*)d_in[6];
  const float* wv = (const float*)d_in[7];
  const float* bv = (const float*)d_in[8];
  const float* wo = (const float*)d_in[9];
  const float* bo = (const float*)d_in[10];
  ushort* ws = (ushort*)d_ws;

  cvt_w<<<2048, 256, 0, stream>>>(wq, wk, wv, wo, ws);
  gemm_qkv<<<dim3(8, 192), 256, 0, stream>>>(xq, xk, xv, ws, ws, bq, bk, bv);
  attn8<<<dim3(16, 32), 512, 0, stream>>>(ws + QB_O, ws + KB_O, ws + VT_O, ws + CTX_O);
  gemm_out<<<dim3(16, 32), 256, 0, stream>>>(ws + CTX_O, ws + WO_O, bo, (float*)d_out);
}

// Round 14
// 109.544 us; speedup vs baseline: 1.0452x; 1.0452x over previous
//
#include <hip/hip_runtime.h>
#include <hip/hip_bf16.h>

using ushort = unsigned short;

typedef __attribute__((ext_vector_type(8))) short bf16x8;
typedef __attribute__((ext_vector_type(4))) float f32x4;
typedef __attribute__((ext_vector_type(16))) float f32x16;
typedef __attribute__((ext_vector_type(4))) unsigned short u16x4;

#define DEVINL __device__ __forceinline__

// ---- problem constants ----
// B=2, S=2048, D=1024, H=16, dk=64, M=B*S=4096

// workspace layout (ushort element offsets)
static constexpr size_t WQ_O = 12582912;       // weights bf16, 1M each (wq,wk,wv,wo)
static constexpr size_t WO_O = 15728640;
static constexpr size_t QB_O = 16777216;       // Q [b][h][s][64]   4M  (scaled by log2e/8)
static constexpr size_t KB_O = 20971520;       // K [b][h][s][64]   4M
static constexpr size_t VT_O = 25165824;       // V^T [b][h][64][s] 4M
static constexpr size_t CTX_O = 0;             // ctx [b][s][1024] bf16

DEVINL ushort f2bf(float f) {
  unsigned u = __builtin_bit_cast(unsigned, f);
  u += 0x7fffu + ((u >> 16) & 1u);   // RNE
  return (ushort)(u >> 16);
}

// async global->LDS DMA, 16B per lane; dst wave-uniform base (HW adds lane*16)
DEVINL void gld16(const ushort* g, ushort* lds) {
  __builtin_amdgcn_global_load_lds(
      (const __attribute__((address_space(1))) void*)g,
      (__attribute__((address_space(3))) void*)lds, 16, 0, 0);
}

// ---------------- fp32 -> bf16 conversion of the 4 weight matrices ----------------
__global__ __launch_bounds__(256) void cvt_w(
    const float* __restrict__ wq, const float* __restrict__ wk,
    const float* __restrict__ wv, const float* __restrict__ wo,
    ushort* __restrict__ ws)
{
  int e = (blockIdx.x * 256 + threadIdx.x) * 8;   // 4M elems total
  const float* s;
  if      (e < 1048576) s = wq + e;
  else if (e < 2097152) s = wk + (e - 1048576);
  else if (e < 3145728) s = wv + (e - 2097152);
  else                  s = wo + (e - 3145728);
  float4 a = *(const float4*)s;
  float4 b = *(const float4*)(s + 4);
  union { u16x4 v; ushort u[4]; } r0, r1;
  r0.u[0] = f2bf(a.x); r0.u[1] = f2bf(a.y); r0.u[2] = f2bf(a.z); r0.u[3] = f2bf(a.w);
  r1.u[0] = f2bf(b.x); r1.u[1] = f2bf(b.y); r1.u[2] = f2bf(b.z); r1.u[3] = f2bf(b.w);
  *(u16x4*)(ws + WQ_O + e) = r0.v;
  *(u16x4*)(ws + WQ_O + e + 4) = r1.v;
}

// ---------------- 128xBN bf16 NT GEMM core, single-barrier double-buffered ----------------
// CVTA: A is fp32, converted to bf16 during LDS staging (v_cvt_pk_bf16_f32).
// Per iter: write tile kt+1 into buf p^1 (readers finished before last barrier) while
// MFMA reads buf p; ONE __syncthreads per iter (was two).
template<bool CVTA, int BN>
DEVINL void gemm_core(const void* __restrict__ Av, const ushort* __restrict__ Bw,
                      const float* __restrict__ bias, void* __restrict__ Cout,
                      float scale, int omode, int row0, int col0)
{
  constexpr int K = 1024;
  constexpr int BI = BN / 32;
  constexpr int NJ = BN / 32;
  __shared__ ushort As[2][128 * 64];
  __shared__ ushort Bs[2][BN * 64];
  const int t = threadIdx.x;
  const int l = t & 63;
  const int w = t >> 6;
  const int wr = w >> 1, wc = w & 1;

  const int srow = t >> 3;
  const int scol8 = (t & 7) * 8;
  const int swz_half = ((((t & 7) * 16) ^ ((srow & 7) << 4)) >> 1);

  const ushort* Ap16 = (const ushort*)Av + (size_t)(row0 + srow) * K + scol8;
  const float*  Ap32 = (const float*)Av + (size_t)(row0 + srow) * K + scol8;
  const ushort* Bp = Bw + (size_t)(col0 + srow) * K + scol8;

  bf16x8 areg[4], breg[BI];
  float4 a32[4][2];
  auto loadstage = [&](int k0) {
#pragma unroll
    for (int i = 0; i < 4; ++i) {
      if constexpr (CVTA) {
        a32[i][0] = *(const float4*)(Ap32 + (size_t)(i * 32) * K + k0);
        a32[i][1] = *(const float4*)(Ap32 + (size_t)(i * 32) * K + k0 + 4);
      } else {
        areg[i] = *(const bf16x8*)(Ap16 + (size_t)(i * 32) * K + k0);
      }
    }
#pragma unroll
    for (int i = 0; i < BI; ++i)
      breg[i] = *(const bf16x8*)(Bp + (size_t)(i * 32) * K + k0);
  };
  auto writestage = [&](int pp) {
#pragma unroll
    for (int i = 0; i < 4; ++i) {
      if constexpr (CVTA) {
        union { bf16x8 v; unsigned u[4]; } pk;
        asm("v_cvt_pk_bf16_f32 %0, %1, %2" : "=v"(pk.u[0]) : "v"(a32[i][0].x), "v"(a32[i][0].y));
        asm("v_cvt_pk_bf16_f32 %0, %1, %2" : "=v"(pk.u[1]) : "v"(a32[i][0].z), "v"(a32[i][0].w));
        asm("v_cvt_pk_bf16_f32 %0, %1, %2" : "=v"(pk.u[2]) : "v"(a32[i][1].x), "v"(a32[i][1].y));
        asm("v_cvt_pk_bf16_f32 %0, %1, %2" : "=v"(pk.u[3]) : "v"(a32[i][1].z), "v"(a32[i][1].w));
        *(bf16x8*)&As[pp][(srow + i * 32) * 64 + swz_half] = pk.v;
      } else {
        *(bf16x8*)&As[pp][(srow + i * 32) * 64 + swz_half] = areg[i];
      }
    }
#pragma unroll
    for (int i = 0; i < BI; ++i)
      *(bf16x8*)&Bs[pp][(srow + i * 32) * 64 + swz_half] = breg[i];
  };

  f32x4 acc[4][NJ];
#pragma unroll
  for (int i = 0; i < 4; ++i)
#pragma unroll
    for (int j = 0; j < NJ; ++j) acc[i][j] = (f32x4){0.f, 0.f, 0.f, 0.f};

  loadstage(0);
  writestage(0);
  loadstage(64);
  __syncthreads();

#pragma unroll 1
  for (int kt = 0; kt < K / 64; ++kt) {
    const int p = kt & 1;
    // write next tile into the buffer MFMA is NOT reading; prefetch tile kt+2
    if (kt + 1 < K / 64) {
      writestage(p ^ 1);
      if (kt + 2 < K / 64) loadstage((kt + 2) * 64);
    }
    const ushort* Al = As[p];
    const ushort* Bl = Bs[p];
#pragma unroll
    for (int ks = 0; ks < 2; ++ks) {
      bf16x8 af[4], bfr[NJ];
#pragma unroll
      for (int mi = 0; mi < 4; ++mi) {
        int r = wr * 64 + mi * 16 + (l & 15);
        int cb = ((ks << 6) | ((l >> 4) << 4)) ^ ((r & 7) << 4);
        af[mi] = *(const bf16x8*)&Al[r * 64 + (cb >> 1)];
      }
#pragma unroll
      for (int nj = 0; nj < NJ; ++nj) {
        int r = wc * (BN / 2) + nj * 16 + (l & 15);
        int cb = ((ks << 6) | ((l >> 4) << 4)) ^ ((r & 7) << 4);
        bfr[nj] = *(const bf16x8*)&Bl[r * 64 + (cb >> 1)];
      }
#pragma unroll
      for (int mi = 0; mi < 4; ++mi)
#pragma unroll
        for (int nj = 0; nj < NJ; ++nj)
          acc[mi][nj] = __builtin_amdgcn_mfma_f32_16x16x32_bf16(af[mi], bfr[nj], acc[mi][nj], 0, 0, 0);
    }
    __syncthreads();
  }

  const int cl = l & 15;
#pragma unroll
  for (int mi = 0; mi < 4; ++mi) {
#pragma unroll
    for (int nj = 0; nj < NJ; ++nj) {
      int n = col0 + wc * (BN / 2) + nj * 16 + cl;
      float bv = bias[n];
      int mbase = row0 + wr * 64 + mi * 16 + (l >> 4) * 4;
      if (omode == 1) {
        float* Of = (float*)Cout;
#pragma unroll
        for (int ri = 0; ri < 4; ++ri)
          Of[(size_t)(mbase + ri) * 1024 + n] = (acc[mi][nj][ri] + bv) * scale;
      } else if (omode == 0) {
        ushort* Ob = (ushort*)Cout;
        int h = n >> 6, d = n & 63;
#pragma unroll
        for (int ri = 0; ri < 4; ++ri) {
          int m = mbase + ri;
          int b = m >> 11, s = m & 2047;
          Ob[(size_t)((b * 16 + h) * 2048 + s) * 64 + d] = f2bf((acc[mi][nj][ri] + bv) * scale);
        }
      } else {  // omode 2: transposed V layout [b][h][d][s]
        ushort* Ob = (ushort*)Cout;
        int h = n >> 6, d = n & 63;
        int b = mbase >> 11, s = mbase & 2047;
        union { u16x4 v; ushort u[4]; } pk;
#pragma unroll
        for (int ri = 0; ri < 4; ++ri) pk.u[ri] = f2bf((acc[mi][nj][ri] + bv) * scale);
        *(u16x4*)&Ob[(size_t)((b * 16 + h) * 64 + d) * 2048 + s] = pk.v;
      }
    }
  }
}

// fused QKV projection + fp32->bf16 A conversion (R12 grid/grouping, bench-proven).
// hw = bx+8by+256z dispatch-linear; X=hw&7 is the XCD. Blocks sharing one fp32 A-panel
// (same z,by) get consecutive hw with hw&7 == X -> one L2 fetch per panel.
__global__ __launch_bounds__(256, 2) void gemm_qkv(
    const float* __restrict__ xq, const float* __restrict__ xk, const float* __restrict__ xv,
    const ushort* __restrict__ ws_c, ushort* __restrict__ ws_m,
    const float* __restrict__ bq, const float* __restrict__ bk, const float* __restrict__ bv)
{
  const int hw = blockIdx.x + 8 * blockIdx.y + 256 * blockIdx.z;
  const int X = hw & 7, j = hw >> 3;
  const int g = 8 * (j >> 3) + X;      // group = (z,by), g&7 == X (stays on XCD X)
  const int bx = j & 7;
  const int by = g & 31, z = g >> 5;

  const float* A = (z == 0) ? xq : ((z == 1) ? xk : xv);
  const ushort* W = ws_c + WQ_O + (size_t)z * 1048576;
  const float* bias = (z == 0) ? bq : ((z == 1) ? bk : bv);
  ushort* dst = ws_m + QB_O + (size_t)z * 4194304;
  float scale = (z == 0) ? (0.125f * 1.4426950408889634f) : 1.0f;  // fold 1/sqrt(dk)*log2e into Q
  int omode = (z == 2) ? 2 : 0;
  gemm_core<true, 128>(A, W, bias, dst, scale, omode, by * 128, bx * 128);
}

// out projection: 128x64 tiles -> 512 blocks = 2 blocks/CU
__global__ __launch_bounds__(256, 2) void gemm_out(
    const ushort* __restrict__ ctx, const ushort* __restrict__ wo,
    const float* __restrict__ bo, float* __restrict__ out)
{
  gemm_core<false, 64>(ctx, wo, bo, out, 1.0f, 1, blockIdx.y * 128, blockIdx.x * 64);
}

// ---------------- flash attention (R10 bench-proven, verbatim) ----------------
__global__ __launch_bounds__(512, 4) void attn8(
    const ushort* __restrict__ Qb, const ushort* __restrict__ Kb,
    const ushort* __restrict__ Vtb, ushort* __restrict__ Ctx)
{
  __shared__ ushort smem[32768];   // 64KB: K[half][buf][4096] | +16384: V[half][buf][4096]

  const int t = threadIdx.x, l = t & 63, w = t >> 6;
  const int wq4 = w & 3, half = w >> 2;
  const int hi2 = l >> 5, q = l & 31;

  // XCD-aware remap: hw dispatch-linear; xcd = hw&7 -> bh%8 == xcd
  const int hw = blockIdx.y * 16 + blockIdx.x;
  const int j = hw >> 3;
  const int bh = (hw & 7) + 8 * (j >> 4);
  const int qt = j & 15;

  const int kvb = half * 1024;
  const ushort* Qp = Qb + ((size_t)bh * 2048 + qt * 128 + wq4 * 32) * 64;
  const ushort* Kp = Kb + (size_t)bh * 2048 * 64;
  const ushort* Vp = Vtb + (size_t)bh * 64 * 2048;

  ushort* Ksh = smem + half * 8192;
  ushort* Vsh = smem + 16384 + half * 8192;

  // Q B-fragments: lane holds Q[q][ks*16 + hi2*8 + j]
  bf16x8 qf[4];
#pragma unroll
  for (int ks = 0; ks < 4; ++ks)
    qf[ks] = *(const bf16x8*)(Qp + q * 64 + ks * 16 + hi2 * 8);

  auto stageKV = [&](int pp, int kv0) {
#pragma unroll
    for (int i = 0; i < 2; ++i) {
      int R = (i * 4 + wq4) * 8 + (l >> 3);                     // LDS row 0..63
      int g = l & 7;                                            // 16B granule
      int sR = (R & ~12) | ((R & 4) << 1) | ((R & 8) >> 1);     // swap bits 2,3
      gld16(Kp + (size_t)(kv0 + sR) * 64 + (g ^ (R & 7)) * 8,
            Ksh + pp * 4096 + (i * 4 + wq4) * 512);
      gld16(Vp + (size_t)R * 2048 + kv0 + (g ^ (R & 7)) * 8,
            Vsh + pp * 4096 + (i * 4 + wq4) * 512);
    }
  };

  f32x16 acc0, acc1;   // N^T: d = db*32 + (reg&3)+8*(reg>>2)+4*hi2, col q
#pragma unroll
  for (int i = 0; i < 16; ++i) { acc0[i] = 0.f; acc1[i] = 0.f; }
  f32x16 Zv;
#pragma unroll
  for (int i = 0; i < 16; ++i) Zv[i] = 0.f;
  float lrun = 0.f;

  const int rsw = (q & 7) << 4;

  stageKV(0, kvb);
  __syncthreads();

#pragma unroll 1
  for (int kt = 0; kt < 16; ++kt) {
    const int p = kt & 1;
    const ushort* Kl = Ksh + p * 4096;
    const ushort* Vl = Vsh + p * 4096;

    // ---- QK burst: both 32-kv chunks (8 MFMA back-to-back, C = persistent zero) ----
    f32x16 scA, scB;
    __builtin_amdgcn_s_setprio(1);
    {
      bf16x8 kf = *(const bf16x8*)&Kl[q * 64 + (((hi2 * 16)) ^ rsw) / 2];
      scA = __builtin_amdgcn_mfma_f32_32x32x16_bf16(kf, qf[0], Zv, 0, 0, 0);
#pragma unroll
      for (int ks = 1; ks < 4; ++ks) {
        bf16x8 k2 = *(const bf16x8*)&Kl[q * 64 + (((ks * 32 + hi2 * 16) ^ rsw) >> 1)];
        scA = __builtin_amdgcn_mfma_f32_32x32x16_bf16(k2, qf[ks], scA, 0, 0, 0);
      }
      const int r1 = (32 + q) * 64;
      bf16x8 kg = *(const bf16x8*)&Kl[r1 + (((hi2 * 16)) ^ rsw) / 2];
      scB = __builtin_amdgcn_mfma_f32_32x32x16_bf16(kg, qf[0], Zv, 0, 0, 0);
#pragma unroll
      for (int ks = 1; ks < 4; ++ks) {
        bf16x8 k2 = *(const bf16x8*)&Kl[r1 + (((ks * 32 + hi2 * 16) ^ rsw) >> 1)];
        scB = __builtin_amdgcn_mfma_f32_32x32x16_bf16(k2, qf[ks], scB, 0, 0, 0);
      }
    }
    __builtin_amdgcn_s_setprio(0);

    if (kt + 1 < 16) stageKV(p ^ 1, kvb + (kt + 1) * 64);

    // ---- per chunk: softmax-lite + pack + PV ----
#pragma unroll
    for (int c = 0; c < 2; ++c) {
      f32x16& sc = (c == 0) ? scA : scB;
      float s0 = 0.f, s1 = 0.f, s2 = 0.f, s3 = 0.f;
#pragma unroll
      for (int i = 0; i < 4; ++i) {
        float e0 = __builtin_amdgcn_exp2f(sc[i]);      sc[i] = e0;      s0 += e0;
        float e1 = __builtin_amdgcn_exp2f(sc[4 + i]);  sc[4 + i] = e1;  s1 += e1;
        float e2 = __builtin_amdgcn_exp2f(sc[8 + i]);  sc[8 + i] = e2;  s2 += e2;
        float e3 = __builtin_amdgcn_exp2f(sc[12 + i]); sc[12 + i] = e3; s3 += e3;
      }
      lrun += (s0 + s1) + (s2 + s3);

      union PU { bf16x8 v; unsigned u[4]; } pA, pB;
#pragma unroll
      for (int i = 0; i < 4; ++i) {
        asm("v_cvt_pk_bf16_f32 %0, %1, %2" : "=v"(pA.u[i]) : "v"(sc[2 * i]), "v"(sc[2 * i + 1]));
        asm("v_cvt_pk_bf16_f32 %0, %1, %2" : "=v"(pB.u[i]) : "v"(sc[8 + 2 * i]), "v"(sc[9 + 2 * i]));
      }

      __builtin_amdgcn_s_setprio(1);
#pragma unroll
      for (int db = 0; db < 2; ++db) {
        const int d = db * 32 + q;
        bf16x8 va = *(const bf16x8*)&Vl[d * 64 + (((c * 64 + hi2 * 16) ^ rsw) >> 1)];
        bf16x8 vb = *(const bf16x8*)&Vl[d * 64 + (((c * 64 + 32 + hi2 * 16) ^ rsw) >> 1)];
        if (db == 0) {
          acc0 = __builtin_amdgcn_mfma_f32_32x32x16_bf16(va, pA.v, acc0, 0, 0, 0);
          acc0 = __builtin_amdgcn_mfma_f32_32x32x16_bf16(vb, pB.v, acc0, 0, 0, 0);
        } else {
          acc1 = __builtin_amdgcn_mfma_f32_32x32x16_bf16(va, pA.v, acc1, 0, 0, 0);
          acc1 = __builtin_amdgcn_mfma_f32_32x32x16_bf16(vb, pB.v, acc1, 0, 0, 0);
        }
      }
      __builtin_amdgcn_s_setprio(0);
    }
    __syncthreads();
  }

  // ===== epilogue: merge halves in LDS (granule-swizzled), coalesced ctx write =====
  float lsum = lrun + __shfl_xor(lrun, 32);
  float* Lf = (float*)smem;

  // phase A: merge row-sums (1KB region)
  if (l < 32) Lf[half * 128 + wq4 * 32 + q] = lsum;
  __syncthreads();
  const float inv = 1.0f / (Lf[wq4 * 32 + q] + Lf[128 + wq4 * 32 + q]);
  __syncthreads();

  // swizzled float4-granule address: row stride 64 floats, G' = G ^ (row&15)
  auto mrg = [&](int row, int G) -> float* {
    return Lf + row * 64 + ((G ^ (row & 15)) << 2);
  };

  // phase B: half1 dumps raw partials
  if (half == 1) {
    const int row = wq4 * 32 + q;
#pragma unroll
    for (int db = 0; db < 2; ++db)
#pragma unroll
      for (int g = 0; g < 4; ++g) {
        float4 v;
        if (db == 0) v = (float4){acc0[g * 4], acc0[g * 4 + 1], acc0[g * 4 + 2], acc0[g * 4 + 3]};
        else         v = (float4){acc1[g * 4], acc1[g * 4 + 1], acc1[g * 4 + 2], acc1[g * 4 + 3]};
        *(float4*)mrg(row, db * 8 + g * 2 + hi2) = v;
      }
  }
  __syncthreads();

  // phase C: half0 merges in place, applying 1/l
  if (half == 0) {
    const int row = wq4 * 32 + q;
#pragma unroll
    for (int db = 0; db < 2; ++db)
#pragma unroll
      for (int g = 0; g < 4; ++g) {
        float* p = mrg(row, db * 8 + g * 2 + hi2);
        float4 pv = *(float4*)p;
        float4 o;
        if (db == 0) o = (float4){(acc0[g * 4] + pv.x) * inv, (acc0[g * 4 + 1] + pv.y) * inv,
                                  (acc0[g * 4 + 2] + pv.z) * inv, (acc0[g * 4 + 3] + pv.w) * inv};
        else         o = (float4){(acc1[g * 4] + pv.x) * inv, (acc1[g * 4 + 1] + pv.y) * inv,
                                  (acc1[g * 4 + 2] + pv.z) * inv, (acc1[g * 4 + 3] + pv.w) * inv};
        *(float4*)p = o;
      }
  }
  __syncthreads();

  // phase D: all 8 waves write ctx; 8 lanes cover one 128B row
  {
    const int b = bh >> 4, h = bh & 15;
    const int d0 = (l & 7) * 8;
#pragma unroll
    for (int rr = 0; rr < 2; ++rr) {
      int row = w * 16 + rr * 8 + (l >> 3);
      float4 f0 = *(const float4*)mrg(row, (l & 7) * 2);
      float4 f1 = *(const float4*)mrg(row, (l & 7) * 2 + 1);
      union { u16x4 v; ushort u[4]; } o0, o1;
      o0.u[0] = f2bf(f0.x); o0.u[1] = f2bf(f0.y); o0.u[2] = f2bf(f0.z); o0.u[3] = f2bf(f0.w);
      o1.u[0] = f2bf(f1.x); o1.u[1] = f2bf(f1.y); o1.u[2] = f2bf(f1.z); o1.u[3] = f2bf(f1.w);
      ushort* dst = Ctx + ((size_t)b * 2048 + qt * 128 + row) * 1024 + h * 64 + d0;
      *(u16x4*)dst = o0.v;
      *(u16x4*)(dst + 4) = o1.v;
    }
  }
}

extern "C" void kernel_launch(void* const* d_in, const int* in_sizes, int n_in,
                              void* d_out, int out_size, void* d_ws, size_t ws_size,
                              hipStream_t stream) {
  const float* xq = (const float*)d_in[0];
  const float* xk = (const float*)d_in[1];
  const float* xv = (const float*)d_in[2];
  const float* wq = (const float*)d_in[3];
  const float* bq = (const float*)d_in[4];
  const float* wk = (const float*)d_in[5];
  const float* bk = (const float*)d_in[6];
  const float* wv = (const float*)d_in[7];
  const float* bv = (const float*)d_in[8];
  const float* wo = (const float*)d_in[9];
  const float* bo = (const float*)d_in[10];
  ushort* ws = (ushort*)d_ws;

  cvt_w<<<2048, 256, 0, stream>>>(wq, wk, wv, wo, ws);
  gemm_qkv<<<dim3(8, 32, 3), 256, 0, stream>>>(xq, xk, xv, ws, ws, bq, bk, bv);
  attn8<<<dim3(16, 32), 512, 0, stream>>>(ws + QB_O, ws + KB_O, ws + VT_O, ws + CTX_O);
  gemm_out<<<dim3(16, 32), 256, 0, stream>>>(ws + CTX_O, ws + WO_O, bo, (float*)d_out);
}

// Round 15
// 103.751 us; speedup vs baseline: 1.1036x; 1.0558x over previous
//
#include <hip/hip_runtime.h>
#include <hip/hip_bf16.h>

using ushort = unsigned short;

typedef __attribute__((ext_vector_type(8))) short bf16x8;
typedef __attribute__((ext_vector_type(4))) float f32x4;
typedef __attribute__((ext_vector_type(16))) float f32x16;
typedef __attribute__((ext_vector_type(4))) unsigned short u16x4;

#define DEVINL __device__ __forceinline__

// ---- problem constants ----
// B=2, S=2048, D=1024, H=16, dk=64, M=B*S=4096

// workspace layout (ushort element offsets)
static constexpr size_t WQ_O = 12582912;       // weights bf16, 1M each (wq,wk,wv,wo)
static constexpr size_t WO_O = 15728640;
static constexpr size_t QB_O = 16777216;       // Q [b][h][s][64]   4M  (scaled by log2e/8)
static constexpr size_t KB_O = 20971520;       // K [b][h][s][64]   4M
static constexpr size_t VT_O = 25165824;       // V^T [b][h][64][s] 4M
static constexpr size_t CTX_O = 0;             // ctx [b][s][1024] bf16

DEVINL ushort f2bf(float f) {
  unsigned u = __builtin_bit_cast(unsigned, f);
  u += 0x7fffu + ((u >> 16) & 1u);   // RNE
  return (ushort)(u >> 16);
}

// async global->LDS DMA, 16B per lane; dst wave-uniform base (HW adds lane*16)
DEVINL void gld16(const ushort* g, ushort* lds) {
  __builtin_amdgcn_global_load_lds(
      (const __attribute__((address_space(1))) void*)g,
      (__attribute__((address_space(3))) void*)lds, 16, 0, 0);
}

// ---- weak barriers: raw s_barrier without the compiler's vmcnt(0) drain ----
// WAR barrier (before LDS overwrite): readers' ds_reads are complete by data-dep
// (their MFMAs consumed the results before reaching here). No waitcnt needed.
DEVINL void barrier_war() {
  __builtin_amdgcn_sched_barrier(0);
  asm volatile("" ::: "memory");
  __builtin_amdgcn_s_barrier();
  __builtin_amdgcn_sched_barrier(0);
}
// RAW barrier (before LDS reads): own ds_writes must be retired -> lgkmcnt(0) only.
// Global prefetch loads (vmcnt) intentionally stay IN FLIGHT across this barrier.
DEVINL void barrier_raw() {
  __builtin_amdgcn_sched_barrier(0);
  asm volatile("s_waitcnt lgkmcnt(0)" ::: "memory");
  __builtin_amdgcn_sched_barrier(0);
  __builtin_amdgcn_s_barrier();
  __builtin_amdgcn_sched_barrier(0);
}

// ---------------- fp32 -> bf16 conversion of the 4 weight matrices ----------------
__global__ __launch_bounds__(256) void cvt_w(
    const float* __restrict__ wq, const float* __restrict__ wk,
    const float* __restrict__ wv, const float* __restrict__ wo,
    ushort* __restrict__ ws)
{
  int e = (blockIdx.x * 256 + threadIdx.x) * 8;   // 4M elems total
  const float* s;
  if      (e < 1048576) s = wq + e;
  else if (e < 2097152) s = wk + (e - 1048576);
  else if (e < 3145728) s = wv + (e - 2097152);
  else                  s = wo + (e - 3145728);
  float4 a = *(const float4*)s;
  float4 b = *(const float4*)(s + 4);
  union { u16x4 v; ushort u[4]; } r0, r1;
  r0.u[0] = f2bf(a.x); r0.u[1] = f2bf(a.y); r0.u[2] = f2bf(a.z); r0.u[3] = f2bf(a.w);
  r1.u[0] = f2bf(b.x); r1.u[1] = f2bf(b.y); r1.u[2] = f2bf(b.z); r1.u[3] = f2bf(b.w);
  *(u16x4*)(ws + WQ_O + e) = r0.v;
  *(u16x4*)(ws + WQ_O + e + 4) = r1.v;
}

// ---------------- 128xBN bf16 NT GEMM core (R12 structure + weak barriers) ----------------
// CVTA: A is fp32, converted to bf16 during LDS staging (v_cvt_pk_bf16_f32).
template<bool CVTA, int BN>
DEVINL void gemm_core(const void* __restrict__ Av, const ushort* __restrict__ Bw,
                      const float* __restrict__ bias, void* __restrict__ Cout,
                      float scale, int omode, int row0, int col0)
{
  constexpr int K = 1024;
  constexpr int BI = BN / 32;
  constexpr int NJ = BN / 32;
  __shared__ ushort As[128 * 64];
  __shared__ ushort Bs[BN * 64];
  const int t = threadIdx.x;
  const int l = t & 63;
  const int w = t >> 6;
  const int wr = w >> 1, wc = w & 1;

  const int srow = t >> 3;
  const int scol8 = (t & 7) * 8;
  const int swz_half = ((((t & 7) * 16) ^ ((srow & 7) << 4)) >> 1);

  const ushort* Ap16 = (const ushort*)Av + (size_t)(row0 + srow) * K + scol8;
  const float*  Ap32 = (const float*)Av + (size_t)(row0 + srow) * K + scol8;
  const ushort* Bp = Bw + (size_t)(col0 + srow) * K + scol8;

  bf16x8 areg[4], breg[BI];
  float4 a32[4][2];
  auto loadstage = [&](int k0) {
#pragma unroll
    for (int i = 0; i < 4; ++i) {
      if constexpr (CVTA) {
        a32[i][0] = *(const float4*)(Ap32 + (size_t)(i * 32) * K + k0);
        a32[i][1] = *(const float4*)(Ap32 + (size_t)(i * 32) * K + k0 + 4);
      } else {
        areg[i] = *(const bf16x8*)(Ap16 + (size_t)(i * 32) * K + k0);
      }
    }
#pragma unroll
    for (int i = 0; i < BI; ++i)
      breg[i] = *(const bf16x8*)(Bp + (size_t)(i * 32) * K + k0);
  };

  f32x4 acc[4][NJ];
#pragma unroll
  for (int i = 0; i < 4; ++i)
#pragma unroll
    for (int j = 0; j < NJ; ++j) acc[i][j] = (f32x4){0.f, 0.f, 0.f, 0.f};

  loadstage(0);
#pragma unroll 1
  for (int kt = 0; kt < K / 64; ++kt) {
    barrier_war();    // all waves done reading LDS (prev MFMA consumed its ds_reads)
#pragma unroll
    for (int i = 0; i < 4; ++i) {
      if constexpr (CVTA) {
        union { bf16x8 v; unsigned u[4]; } pk;
        asm("v_cvt_pk_bf16_f32 %0, %1, %2" : "=v"(pk.u[0]) : "v"(a32[i][0].x), "v"(a32[i][0].y));
        asm("v_cvt_pk_bf16_f32 %0, %1, %2" : "=v"(pk.u[1]) : "v"(a32[i][0].z), "v"(a32[i][0].w));
        asm("v_cvt_pk_bf16_f32 %0, %1, %2" : "=v"(pk.u[2]) : "v"(a32[i][1].x), "v"(a32[i][1].y));
        asm("v_cvt_pk_bf16_f32 %0, %1, %2" : "=v"(pk.u[3]) : "v"(a32[i][1].z), "v"(a32[i][1].w));
        *(bf16x8*)&As[(srow + i * 32) * 64 + swz_half] = pk.v;
      } else {
        *(bf16x8*)&As[(srow + i * 32) * 64 + swz_half] = areg[i];
      }
    }
#pragma unroll
    for (int i = 0; i < BI; ++i)
      *(bf16x8*)&Bs[(srow + i * 32) * 64 + swz_half] = breg[i];
    if (kt + 1 < K / 64) loadstage((kt + 1) * 64);   // prefetch: stays in flight past barrier
    barrier_raw();    // lgkmcnt(0) only -- no vmcnt drain
#pragma unroll
    for (int ks = 0; ks < 2; ++ks) {
      bf16x8 af[4], bfr[NJ];
#pragma unroll
      for (int mi = 0; mi < 4; ++mi) {
        int r = wr * 64 + mi * 16 + (l & 15);
        int cb = ((ks << 6) | ((l >> 4) << 4)) ^ ((r & 7) << 4);
        af[mi] = *(const bf16x8*)&As[r * 64 + (cb >> 1)];
      }
#pragma unroll
      for (int nj = 0; nj < NJ; ++nj) {
        int r = wc * (BN / 2) + nj * 16 + (l & 15);
        int cb = ((ks << 6) | ((l >> 4) << 4)) ^ ((r & 7) << 4);
        bfr[nj] = *(const bf16x8*)&Bs[r * 64 + (cb >> 1)];
      }
#pragma unroll
      for (int mi = 0; mi < 4; ++mi)
#pragma unroll
        for (int nj = 0; nj < NJ; ++nj)
          acc[mi][nj] = __builtin_amdgcn_mfma_f32_16x16x32_bf16(af[mi], bfr[nj], acc[mi][nj], 0, 0, 0);
    }
  }

  const int cl = l & 15;
#pragma unroll
  for (int mi = 0; mi < 4; ++mi) {
#pragma unroll
    for (int nj = 0; nj < NJ; ++nj) {
      int n = col0 + wc * (BN / 2) + nj * 16 + cl;
      float bv = bias[n];
      int mbase = row0 + wr * 64 + mi * 16 + (l >> 4) * 4;
      if (omode == 1) {
        float* Of = (float*)Cout;
#pragma unroll
        for (int ri = 0; ri < 4; ++ri)
          Of[(size_t)(mbase + ri) * 1024 + n] = (acc[mi][nj][ri] + bv) * scale;
      } else if (omode == 0) {
        ushort* Ob = (ushort*)Cout;
        int h = n >> 6, d = n & 63;
#pragma unroll
        for (int ri = 0; ri < 4; ++ri) {
          int m = mbase + ri;
          int b = m >> 11, s = m & 2047;
          Ob[(size_t)((b * 16 + h) * 2048 + s) * 64 + d] = f2bf((acc[mi][nj][ri] + bv) * scale);
        }
      } else {  // omode 2: transposed V layout [b][h][d][s]
        ushort* Ob = (ushort*)Cout;
        int h = n >> 6, d = n & 63;
        int b = mbase >> 11, s = mbase & 2047;
        union { u16x4 v; ushort u[4]; } pk;
#pragma unroll
        for (int ri = 0; ri < 4; ++ri) pk.u[ri] = f2bf((acc[mi][nj][ri] + bv) * scale);
        *(u16x4*)&Ob[(size_t)((b * 16 + h) * 64 + d) * 2048 + s] = pk.v;
      }
    }
  }
}

// fused QKV projection + fp32->bf16 A conversion (R12 grid/grouping, bench-proven).
// hw = bx+8by+256z dispatch-linear; X=hw&7 is the XCD. Blocks sharing one fp32 A-panel
// (same z,by) get consecutive hw with hw&7 == X -> one L2 fetch per panel.
__global__ __launch_bounds__(256, 2) void gemm_qkv(
    const float* __restrict__ xq, const float* __restrict__ xk, const float* __restrict__ xv,
    const ushort* __restrict__ ws_c, ushort* __restrict__ ws_m,
    const float* __restrict__ bq, const float* __restrict__ bk, const float* __restrict__ bv)
{
  const int hw = blockIdx.x + 8 * blockIdx.y + 256 * blockIdx.z;
  const int X = hw & 7, j = hw >> 3;
  const int g = 8 * (j >> 3) + X;      // group = (z,by), g&7 == X (stays on XCD X)
  const int bx = j & 7;
  const int by = g & 31, z = g >> 5;

  const float* A = (z == 0) ? xq : ((z == 1) ? xk : xv);
  const ushort* W = ws_c + WQ_O + (size_t)z * 1048576;
  const float* bias = (z == 0) ? bq : ((z == 1) ? bk : bv);
  ushort* dst = ws_m + QB_O + (size_t)z * 4194304;
  float scale = (z == 0) ? (0.125f * 1.4426950408889634f) : 1.0f;  // fold 1/sqrt(dk)*log2e into Q
  int omode = (z == 2) ? 2 : 0;
  gemm_core<true, 128>(A, W, bias, dst, scale, omode, by * 128, bx * 128);
}

// out projection: 128x64 tiles -> 512 blocks = 2 blocks/CU
__global__ __launch_bounds__(256, 2) void gemm_out(
    const ushort* __restrict__ ctx, const ushort* __restrict__ wo,
    const float* __restrict__ bo, float* __restrict__ out)
{
  gemm_core<false, 64>(ctx, wo, bo, out, 1.0f, 1, blockIdx.y * 128, blockIdx.x * 64);
}

// ---------------- flash attention (R10 bench-proven, verbatim) ----------------
__global__ __launch_bounds__(512, 4) void attn8(
    const ushort* __restrict__ Qb, const ushort* __restrict__ Kb,
    const ushort* __restrict__ Vtb, ushort* __restrict__ Ctx)
{
  __shared__ ushort smem[32768];   // 64KB: K[half][buf][4096] | +16384: V[half][buf][4096]

  const int t = threadIdx.x, l = t & 63, w = t >> 6;
  const int wq4 = w & 3, half = w >> 2;
  const int hi2 = l >> 5, q = l & 31;

  // XCD-aware remap: hw dispatch-linear; xcd = hw&7 -> bh%8 == xcd
  const int hw = blockIdx.y * 16 + blockIdx.x;
  const int j = hw >> 3;
  const int bh = (hw & 7) + 8 * (j >> 4);
  const int qt = j & 15;

  const int kvb = half * 1024;
  const ushort* Qp = Qb + ((size_t)bh * 2048 + qt * 128 + wq4 * 32) * 64;
  const ushort* Kp = Kb + (size_t)bh * 2048 * 64;
  const ushort* Vp = Vtb + (size_t)bh * 64 * 2048;

  ushort* Ksh = smem + half * 8192;
  ushort* Vsh = smem + 16384 + half * 8192;

  // Q B-fragments: lane holds Q[q][ks*16 + hi2*8 + j]
  bf16x8 qf[4];
#pragma unroll
  for (int ks = 0; ks < 4; ++ks)
    qf[ks] = *(const bf16x8*)(Qp + q * 64 + ks * 16 + hi2 * 8);

  auto stageKV = [&](int pp, int kv0) {
#pragma unroll
    for (int i = 0; i < 2; ++i) {
      int R = (i * 4 + wq4) * 8 + (l >> 3);                     // LDS row 0..63
      int g = l & 7;                                            // 16B granule
      int sR = (R & ~12) | ((R & 4) << 1) | ((R & 8) >> 1);     // swap bits 2,3
      gld16(Kp + (size_t)(kv0 + sR) * 64 + (g ^ (R & 7)) * 8,
            Ksh + pp * 4096 + (i * 4 + wq4) * 512);
      gld16(Vp + (size_t)R * 2048 + kv0 + (g ^ (R & 7)) * 8,
            Vsh + pp * 4096 + (i * 4 + wq4) * 512);
    }
  };

  f32x16 acc0, acc1;   // N^T: d = db*32 + (reg&3)+8*(reg>>2)+4*hi2, col q
#pragma unroll
  for (int i = 0; i < 16; ++i) { acc0[i] = 0.f; acc1[i] = 0.f; }
  f32x16 Zv;
#pragma unroll
  for (int i = 0; i < 16; ++i) Zv[i] = 0.f;
  float lrun = 0.f;

  const int rsw = (q & 7) << 4;

  stageKV(0, kvb);
  __syncthreads();

#pragma unroll 1
  for (int kt = 0; kt < 16; ++kt) {
    const int p = kt & 1;
    const ushort* Kl = Ksh + p * 4096;
    const ushort* Vl = Vsh + p * 4096;

    // ---- QK burst: both 32-kv chunks (8 MFMA back-to-back, C = persistent zero) ----
    f32x16 scA, scB;
    __builtin_amdgcn_s_setprio(1);
    {
      bf16x8 kf = *(const bf16x8*)&Kl[q * 64 + (((hi2 * 16)) ^ rsw) / 2];
      scA = __builtin_amdgcn_mfma_f32_32x32x16_bf16(kf, qf[0], Zv, 0, 0, 0);
#pragma unroll
      for (int ks = 1; ks < 4; ++ks) {
        bf16x8 k2 = *(const bf16x8*)&Kl[q * 64 + (((ks * 32 + hi2 * 16) ^ rsw) >> 1)];
        scA = __builtin_amdgcn_mfma_f32_32x32x16_bf16(k2, qf[ks], scA, 0, 0, 0);
      }
      const int r1 = (32 + q) * 64;
      bf16x8 kg = *(const bf16x8*)&Kl[r1 + (((hi2 * 16)) ^ rsw) / 2];
      scB = __builtin_amdgcn_mfma_f32_32x32x16_bf16(kg, qf[0], Zv, 0, 0, 0);
#pragma unroll
      for (int ks = 1; ks < 4; ++ks) {
        bf16x8 k2 = *(const bf16x8*)&Kl[r1 + (((ks * 32 + hi2 * 16) ^ rsw) >> 1)];
        scB = __builtin_amdgcn_mfma_f32_32x32x16_bf16(k2, qf[ks], scB, 0, 0, 0);
      }
    }
    __builtin_amdgcn_s_setprio(0);

    if (kt + 1 < 16) stageKV(p ^ 1, kvb + (kt + 1) * 64);

    // ---- per chunk: softmax-lite + pack + PV ----
#pragma unroll
    for (int c = 0; c < 2; ++c) {
      f32x16& sc = (c == 0) ? scA : scB;
      float s0 = 0.f, s1 = 0.f, s2 = 0.f, s3 = 0.f;
#pragma unroll
      for (int i = 0; i < 4; ++i) {
        float e0 = __builtin_amdgcn_exp2f(sc[i]);      sc[i] = e0;      s0 += e0;
        float e1 = __builtin_amdgcn_exp2f(sc[4 + i]);  sc[4 + i] = e1;  s1 += e1;
        float e2 = __builtin_amdgcn_exp2f(sc[8 + i]);  sc[8 + i] = e2;  s2 += e2;
        float e3 = __builtin_amdgcn_exp2f(sc[12 + i]); sc[12 + i] = e3; s3 += e3;
      }
      lrun += (s0 + s1) + (s2 + s3);

      union PU { bf16x8 v; unsigned u[4]; } pA, pB;
#pragma unroll
      for (int i = 0; i < 4; ++i) {
        asm("v_cvt_pk_bf16_f32 %0, %1, %2" : "=v"(pA.u[i]) : "v"(sc[2 * i]), "v"(sc[2 * i + 1]));
        asm("v_cvt_pk_bf16_f32 %0, %1, %2" : "=v"(pB.u[i]) : "v"(sc[8 + 2 * i]), "v"(sc[9 + 2 * i]));
      }

      __builtin_amdgcn_s_setprio(1);
#pragma unroll
      for (int db = 0; db < 2; ++db) {
        const int d = db * 32 + q;
        bf16x8 va = *(const bf16x8*)&Vl[d * 64 + (((c * 64 + hi2 * 16) ^ rsw) >> 1)];
        bf16x8 vb = *(const bf16x8*)&Vl[d * 64 + (((c * 64 + 32 + hi2 * 16) ^ rsw) >> 1)];
        if (db == 0) {
          acc0 = __builtin_amdgcn_mfma_f32_32x32x16_bf16(va, pA.v, acc0, 0, 0, 0);
          acc0 = __builtin_amdgcn_mfma_f32_32x32x16_bf16(vb, pB.v, acc0, 0, 0, 0);
        } else {
          acc1 = __builtin_amdgcn_mfma_f32_32x32x16_bf16(va, pA.v, acc1, 0, 0, 0);
          acc1 = __builtin_amdgcn_mfma_f32_32x32x16_bf16(vb, pB.v, acc1, 0, 0, 0);
        }
      }
      __builtin_amdgcn_s_setprio(0);
    }
    __syncthreads();
  }

  // ===== epilogue: merge halves in LDS (granule-swizzled), coalesced ctx write =====
  float lsum = lrun + __shfl_xor(lrun, 32);
  float* Lf = (float*)smem;

  // phase A: merge row-sums (1KB region)
  if (l < 32) Lf[half * 128 + wq4 * 32 + q] = lsum;
  __syncthreads();
  const float inv = 1.0f / (Lf[wq4 * 32 + q] + Lf[128 + wq4 * 32 + q]);
  __syncthreads();

  // swizzled float4-granule address: row stride 64 floats, G' = G ^ (row&15)
  auto mrg = [&](int row, int G) -> float* {
    return Lf + row * 64 + ((G ^ (row & 15)) << 2);
  };

  // phase B: half1 dumps raw partials
  if (half == 1) {
    const int row = wq4 * 32 + q;
#pragma unroll
    for (int db = 0; db < 2; ++db)
#pragma unroll
      for (int g = 0; g < 4; ++g) {
        float4 v;
        if (db == 0) v = (float4){acc0[g * 4], acc0[g * 4 + 1], acc0[g * 4 + 2], acc0[g * 4 + 3]};
        else         v = (float4){acc1[g * 4], acc1[g * 4 + 1], acc1[g * 4 + 2], acc1[g * 4 + 3]};
        *(float4*)mrg(row, db * 8 + g * 2 + hi2) = v;
      }
  }
  __syncthreads();

  // phase C: half0 merges in place, applying 1/l
  if (half == 0) {
    const int row = wq4 * 32 + q;
#pragma unroll
    for (int db = 0; db < 2; ++db)
#pragma unroll
      for (int g = 0; g < 4; ++g) {
        float* p = mrg(row, db * 8 + g * 2 + hi2);
        float4 pv = *(float4*)p;
        float4 o;
        if (db == 0) o = (float4){(acc0[g * 4] + pv.x) * inv, (acc0[g * 4 + 1] + pv.y) * inv,
                                  (acc0[g * 4 + 2] + pv.z) * inv, (acc0[g * 4 + 3] + pv.w) * inv};
        else         o = (float4){(acc1[g * 4] + pv.x) * inv, (acc1[g * 4 + 1] + pv.y) * inv,
                                  (acc1[g * 4 + 2] + pv.z) * inv, (acc1[g * 4 + 3] + pv.w) * inv};
        *(float4*)p = o;
      }
  }
  __syncthreads();

  // phase D: all 8 waves write ctx; 8 lanes cover one 128B row
  {
    const int b = bh >> 4, h = bh & 15;
    const int d0 = (l & 7) * 8;
#pragma unroll
    for (int rr = 0; rr < 2; ++rr) {
      int row = w * 16 + rr * 8 + (l >> 3);
      float4 f0 = *(const float4*)mrg(row, (l & 7) * 2);
      float4 f1 = *(const float4*)mrg(row, (l & 7) * 2 + 1);
      union { u16x4 v; ushort u[4]; } o0, o1;
      o0.u[0] = f2bf(f0.x); o0.u[1] = f2bf(f0.y); o0.u[2] = f2bf(f0.z); o0.u[3] = f2bf(f0.w);
      o1.u[0] = f2bf(f1.x); o1.u[1] = f2bf(f1.y); o1.u[2] = f2bf(f1.z); o1.u[3] = f2bf(f1.w);
      ushort* dst = Ctx + ((size_t)b * 2048 + qt * 128 + row) * 1024 + h * 64 + d0;
      *(u16x4*)dst = o0.v;
      *(u16x4*)(dst + 4) = o1.v;
    }
  }
}

extern "C" void kernel_launch(void* const* d_in, const int* in_sizes, int n_in,
                              void* d_out, int out_size, void* d_ws, size_t ws_size,
                              hipStream_t stream) {
  const float* xq = (const float*)d_in[0];
  const float* xk = (const float*)d_in[1];
  const float* xv = (const float*)d_in[2];
  const float* wq = (const float*)d_in[3];
  const float* bq = (const float*)d_in[4];
  const float* wk = (const float*)d_in[5];
  const float* bk = (const float*)d_in[6];
  const float* wv = (const float*)d_in[7];
  const float* bv = (const float*)d_in[8];
  const float* wo = (const float*)d_in[9];
  const float* bo = (const float*)d_in[10];
  ushort* ws = (ushort*)d_ws;

  cvt_w<<<2048, 256, 0, stream>>>(wq, wk, wv, wo, ws);
  gemm_qkv<<<dim3(8, 32, 3), 256, 0, stream>>>(xq, xk, xv, ws, ws, bq, bk, bv);
  attn8<<<dim3(16, 32), 512, 0, stream>>>(ws + QB_O, ws + KB_O, ws + VT_O, ws + CTX_O);
  gemm_out<<<dim3(16, 32), 256, 0, stream>>>(ws + CTX_O, ws + WO_O, bo, (float*)d_out);
}